// Round 6
// baseline (1134.881 us; speedup 1.0000x reference)
//
#include <hip/hip_runtime.h>

// 3-layer tanh RNN: persistent pipeline, SPLIT-MATRIX 6-wave blocks.
// Wave w = 2l+p (l=layer, p: A=input-proj, B=recurrence). Each wave holds
// exactly ONE 64x64 weight matrix in VGPRs (64 regs) so total per-wave need
// (~110) fits the 128-reg tier the allocator demonstrably picks -> no spill
// (rounds 1/3/4/5 all spilled because need > 128).
// Pipeline offset = w; depth-2 parity LDS rings; RAW s_barrier + lgkmcnt(0)
// per step (NOT __syncthreads: its implicit vmcnt(0) drained wave-0's x
// prefetch HBM loads at every barrier, ~900cy/step for the whole block).
// RPB=2 rows/block -> grid 512 x 6 waves = 3072 waves = 3/EU, fully resident.
//
// Dataflow at global step s (t_w = s - w):
//   (l,A): xc_t = Wih_l . in_t        in = x (l=0) or h^{l-1} (read bcast)
//   (l,B): h_t  = tanh(xc_t + Whh_l . h_{t-1} + bih+bhh)
// Ring freshness verified: every read is of a slot written exactly one
// barrier earlier; overwrites land >=1 barrier after the last read.

typedef __attribute__((ext_vector_type(2))) float f32x2;
typedef __attribute__((ext_vector_type(4))) float f32x4;

#define RNN_B 1024
#define RNN_T 512
#define RNN_H 64
#define RNN_L 3
#define RPB   2                 // batch rows per block
#define NW    (2 * RNN_L)       // 6 waves per block
#define STEPS (RNN_T + NW - 1)  // 517

static __device__ __forceinline__ f32x2 mk2(float a, float b) {
    f32x2 r; r.x = a; r.y = b; return r;
}

__global__ __launch_bounds__(NW * 64)
__attribute__((amdgpu_waves_per_eu(3, 3)))
void rnn_pipeline(const float* __restrict__ x,     // [B,T,H]
                  const float* __restrict__ Wih,   // [L,H,H]
                  const float* __restrict__ Whh,   // [L,H,H]
                  const float* __restrict__ bih,   // [L,H]
                  const float* __restrict__ bhh,   // [L,H]
                  const float* __restrict__ fcw,   // [H]
                  const float* __restrict__ fcb,   // [1]
                  float* __restrict__ out)         // [B]
{
    __shared__ f32x4 xring[2][RPB][RNN_H / 4];             // x bcast staging
    __shared__ f32x4 hring[RNN_L][2][RPB][RNN_H / 4];      // h bcast rings
    __shared__ float xcring[RNN_L][2][RPB][RNN_H];         // xc elementwise

    const int lane = threadIdx.x & 63;
    const int w    = threadIdx.x >> 6;        // 0..5 = pipeline offset
    const int l    = w >> 1;
    const int isA  = !(w & 1);
    const int b0   = blockIdx.x * RPB;

    // ---- ONE weight matrix per wave: row `lane` into 32 f32x2 = 64 VGPRs ----
    f32x2 wt[RNN_H / 2];
    {
        const float* Wsrc = isA ? (Wih + ((size_t)l * RNN_H + lane) * RNN_H)
                                : (Whh + ((size_t)l * RNN_H + lane) * RNN_H);
        const f32x4* wr = (const f32x4*)Wsrc;
#pragma unroll
        for (int c = 0; c < RNN_H / 4; ++c) {
            f32x4 a = wr[c];
            wt[2*c+0] = mk2(a.x, a.y);
            wt[2*c+1] = mk2(a.z, a.w);
        }
    }
#pragma unroll
    for (int i = 0; i < RNN_H / 2; ++i)
        asm volatile("" : "+v"(wt[i]));       // keep resident

    const float bias = bih[l * RNN_H + lane] + bhh[l * RNN_H + lane]; // B-waves
    const float fw   = fcw[lane];
    const float fb   = fcb[0];

    // Zero h rings (waves 0..2 each zero one layer's ring, both slots/rows).
    if (w < RNN_L) {
#pragma unroll
        for (int sl = 0; sl < 2; ++sl)
#pragma unroll
            for (int r = 0; r < RPB; ++r)
                ((float*)&hring[w][sl][r][0])[lane] = 0.0f;
    }

    // Wave 0 ((0,A)) owns x: publish x_0, 3-deep register prefetch pipeline.
    const float* xb = x + (size_t)b0 * RNN_T * RNN_H;
    const size_t rs = (size_t)RNN_T * RNN_H;  // row stride
    float xr0 = 0.f, xr1 = 0.f, xn10 = 0.f, xn11 = 0.f, xn20 = 0.f, xn21 = 0.f;
    if (w == 0) {
        ((float*)&xring[0][0][0])[lane] = xb[lane];
        ((float*)&xring[0][1][0])[lane] = xb[rs + lane];
        xr0  = xb[1 * RNN_H + lane];  xr1  = xb[rs + 1 * RNN_H + lane];
        xn10 = xb[2 * RNN_H + lane];  xn11 = xb[rs + 2 * RNN_H + lane];
        xn20 = xb[3 * RNN_H + lane];  xn21 = xb[rs + 3 * RNN_H + lane];
    }
    __syncthreads();   // entry barrier (one-time full drain is fine)

    float hv0 = 0.0f, hv1 = 0.0f;

    for (int s = 0; s < STEPS; ++s) {
        const int t = s - w;
        const bool active = (t >= 0) && (t < RNN_T);     // wave-uniform
        if (active) {
            const int si = t & 1;
            if (isA) {
                // ---- xc_t = Wih_l . in_t  (in: x or h^{l-1}, bcast reads)
                const f32x4* in0 = (l == 0) ? &xring[si][0][0]
                                            : &hring[l - 1][si][0][0];
                const f32x4* in1 = (l == 0) ? &xring[si][1][0]
                                            : &hring[l - 1][si][1][0];
                f32x2 a00 = mk2(0.f, 0.f), a01 = mk2(0.f, 0.f);
                f32x2 a10 = mk2(0.f, 0.f), a11 = mk2(0.f, 0.f);
#pragma unroll
                for (int c = 0; c < RNN_H / 4; ++c) {
                    f32x4 v0 = in0[c];                   // 64-lane broadcast
                    f32x4 v1 = in1[c];
                    a00 += mk2(v0.x, v0.y) * wt[2*c+0];
                    a01 += mk2(v0.z, v0.w) * wt[2*c+1];
                    a10 += mk2(v1.x, v1.y) * wt[2*c+0];
                    a11 += mk2(v1.z, v1.w) * wt[2*c+1];
                }
                const f32x2 s0 = a00 + a01, s1 = a10 + a11;
                xcring[l][si][0][lane] = s0.x + s0.y;
                xcring[l][si][1][lane] = s1.x + s1.y;

                if (w == 0) {                            // x feeder
                    if (t + 1 < RNN_T) {
                        ((float*)&xring[(t + 1) & 1][0][0])[lane] = xr0;
                        ((float*)&xring[(t + 1) & 1][1][0])[lane] = xr1;
                    }
                    xr0 = xn10; xr1 = xn11;
                    xn10 = xn20; xn11 = xn21;
                    const int tn = (t + 4 < RNN_T) ? (t + 4) : (RNN_T - 1);
                    xn20 = xb[(size_t)tn * RNN_H + lane];
                    xn21 = xb[rs + (size_t)tn * RNN_H + lane];
                }
            } else {
                // ---- h_t = tanh(xc_t + Whh_l . h_{t-1} + bias)
                const int sh = (t - 1) & 1;
                f32x2 a00 = mk2(0.f, 0.f), a01 = mk2(0.f, 0.f);
                f32x2 a10 = mk2(0.f, 0.f), a11 = mk2(0.f, 0.f);
#pragma unroll
                for (int c = 0; c < RNN_H / 4; ++c) {
                    f32x4 u0 = hring[l][sh][0][c];       // broadcast
                    f32x4 u1 = hring[l][sh][1][c];
                    a00 += mk2(u0.x, u0.y) * wt[2*c+0];
                    a01 += mk2(u0.z, u0.w) * wt[2*c+1];
                    a10 += mk2(u1.x, u1.y) * wt[2*c+0];
                    a11 += mk2(u1.z, u1.w) * wt[2*c+1];
                }
                const f32x2 s0 = a00 + a01, s1 = a10 + a11;
                const float pre0 = s0.x + s0.y + bias + xcring[l][si][0][lane];
                const float pre1 = s1.x + s1.y + bias + xcring[l][si][1][lane];

                const float ax0 = fabsf(pre0);
                const float e0  = __expf(-2.0f * ax0);
                hv0 = copysignf((1.0f - e0) / (1.0f + e0), pre0);
                const float ax1 = fabsf(pre1);
                const float e1  = __expf(-2.0f * ax1);
                hv1 = copysignf((1.0f - e1) / (1.0f + e1), pre1);

                ((float*)&hring[l][si][0][0])[lane] = hv0;  // publish h_t
                ((float*)&hring[l][si][1][0])[lane] = hv1;

                if (w == NW - 1 && t == RNN_T - 1) {        // FC head
                    float p0 = hv0 * fw, p1 = hv1 * fw;
#pragma unroll
                    for (int off = 32; off > 0; off >>= 1) {
                        p0 += __shfl_xor(p0, off, 64);
                        p1 += __shfl_xor(p1, off, 64);
                    }
                    if (lane == 0) {
                        out[b0 + 0] = p0 + fb;
                        out[b0 + 1] = p1 + fb;
                    }
                }
            }
        }
        // Raw barrier: drain LDS only; global x prefetches stay in flight
        // across the barrier (compiler inserts counted vmcnt at their use).
        asm volatile("s_waitcnt lgkmcnt(0)" ::: "memory");
        __builtin_amdgcn_s_barrier();
    }
}

extern "C" void kernel_launch(void* const* d_in, const int* in_sizes, int n_in,
                              void* d_out, int out_size, void* d_ws, size_t ws_size,
                              hipStream_t stream)
{
    const float* x   = (const float*)d_in[0];
    const float* Wih = (const float*)d_in[1];
    const float* Whh = (const float*)d_in[2];
    const float* bih = (const float*)d_in[3];
    const float* bhh = (const float*)d_in[4];
    const float* fcw = (const float*)d_in[5];
    const float* fcb = (const float*)d_in[6];
    float* out = (float*)d_out;                // [B,1]

    rnn_pipeline<<<dim3(RNN_B / RPB), dim3(NW * 64), 0, stream>>>(
        x, Wih, Whh, bih, bhh, fcw, fcb, out);
}